// Round 1
// baseline (16820.244 us; speedup 1.0000x reference)
//
#include <hip/hip_runtime.h>

typedef unsigned short u16;
typedef __attribute__((ext_vector_type(8))) short s16x8;
typedef __attribute__((ext_vector_type(4))) short s16x4;
typedef __attribute__((ext_vector_type(4))) float f32x4;

#define MFMA16(a, b, c) __builtin_amdgcn_mfma_f32_16x16x32_bf16(a, b, c, 0, 0, 0)

__device__ __forceinline__ u16 f2bf(float f) {
  unsigned u = __float_as_uint(f);
  u += 0x7FFFu + ((u >> 16) & 1u);
  return (u16)(u >> 16);
}

// async 16B global->LDS. LDS side must be wave-uniform base + lane*16.
__device__ __forceinline__ void async_cp16(const u16* g, u16* l) {
  __builtin_amdgcn_global_load_lds(
      (__attribute__((address_space(1))) void*)g,
      (__attribute__((address_space(3))) void*)l,
      16, 0, 0);
}

// ---------------- conversion kernels ----------------
__global__ void cvt4(const float* __restrict__ s, u16* __restrict__ d, int n4) {
  int i = blockIdx.x * 256 + threadIdx.x;
  if (i >= n4) return;
  f32x4 v = *(const f32x4*)(s + 4L * i);
  s16x4 o;
  o[0] = (short)f2bf(v[0]); o[1] = (short)f2bf(v[1]);
  o[2] = (short)f2bf(v[2]); o[3] = (short)f2bf(v[3]);
  *(s16x4*)(d + 4L * i) = o;
}

// final_weight [256][256] fp32 -> transposed bf16 (fwT[j][k] = fw[k][j])
__global__ void cvt_t(const float* __restrict__ s, u16* __restrict__ d) {
  int j = blockIdx.x, k = threadIdx.x;
  d[j * 256 + k] = f2bf(s[k * 256 + j]);
}

// ---------------- unified BT-GEMM ----------------
// C[i][j] = sum_k A[i][k] * B[j][k]  (+bias, activation per MODE)
// A: [Ma][256] bf16 row-major, B: [Nb][256] bf16 row-major. K = 256 fixed.
// MODE 0: +bias[col] -> bf16      (Q, K projections)
// MODE 1: +bias[row] -> bf16      (V^T projection)
// MODE 2: relu(+bias[col]) -> bf16 (MLP layers)
// MODE 3: sigmoid(C)+bias[col] -> fp32 (final)
template <int MODE>
__global__ __launch_bounds__(256, 4) void gemm_bt(
    const u16* __restrict__ A, const u16* __restrict__ B, void* __restrict__ Cout,
    const float* __restrict__ bias, int Ma, int Nb,
    long aStride, long bStride, long cStride, long biasStride) {
  __shared__ __align__(16) u16 lds[16384];  // A: [128][64], B: [128][64] (swizzled 16B blocks)
  const int tid = threadIdx.x;
  const int lane = tid & 63;
  const int l15 = lane & 15, q4 = lane >> 4;
  const int w = tid >> 6;
  const int qm = w >> 1, qn = w & 1;
  const int g = blockIdx.y;
  A += (long)g * aStride;
  B += (long)g * bStride;
  bias += (long)g * biasStride;
  const int tiles_n = Nb >> 7;
  const int tm = blockIdx.x / tiles_n, tn = blockIdx.x % tiles_n;
  const int row0 = tm << 7, col0 = tn << 7;

  f32x4 C[4][4];
#pragma unroll
  for (int i = 0; i < 4; ++i)
#pragma unroll
    for (int j = 0; j < 4; ++j) C[i][j] = (f32x4)0.0f;

  u16* Al = lds;
  u16* Bl = lds + 8192;

  for (int kc = 0; kc < 4; ++kc) {
    __syncthreads();
#pragma unroll
    for (int i = 0; i < 4; ++i) {  // A: 1024 16B blocks
      int s = tid + i * 256;
      int r = s >> 3, p = s & 7;
      async_cp16(A + (long)(row0 + r) * 256 + kc * 64 + ((p ^ (r & 7)) << 3), Al + s * 8);
    }
#pragma unroll
    for (int i = 0; i < 4; ++i) {  // B: 1024 16B blocks
      int s = tid + i * 256;
      int r = s >> 3, p = s & 7;
      async_cp16(B + (long)(col0 + r) * 256 + kc * 64 + ((p ^ (r & 7)) << 3), Bl + s * 8);
    }
    __syncthreads();
#pragma unroll
    for (int ks = 0; ks < 2; ++ks) {
      s16x8 a[4];
#pragma unroll
      for (int mt = 0; mt < 4; ++mt) {
        int r = qm * 64 + mt * 16 + l15;
        int kb = ks * 4 + q4;
        a[mt] = *(const s16x8*)(Al + r * 64 + ((kb ^ (r & 7)) << 3));
      }
#pragma unroll
      for (int nt = 0; nt < 4; ++nt) {
        int rn = qn * 64 + nt * 16 + l15;
        int kb = ks * 4 + q4;
        s16x8 b = *(const s16x8*)(Bl + rn * 64 + ((kb ^ (rn & 7)) << 3));
#pragma unroll
        for (int mt = 0; mt < 4; ++mt) C[mt][nt] = MFMA16(a[mt], b, C[mt][nt]);
      }
    }
  }

  const int gr0 = row0 + qm * 64, gc0 = col0 + qn * 64;
  float bm[4][4];
  if (MODE == 1) {
#pragma unroll
    for (int mt = 0; mt < 4; ++mt)
#pragma unroll
      for (int e = 0; e < 4; ++e) bm[mt][e] = bias[gr0 + mt * 16 + q4 * 4 + e];
  }
#pragma unroll
  for (int nt = 0; nt < 4; ++nt) {
    int cc = gc0 + nt * 16 + l15;
    float bc = (MODE != 1) ? bias[cc] : 0.0f;
#pragma unroll
    for (int mt = 0; mt < 4; ++mt) {
#pragma unroll
      for (int e = 0; e < 4; ++e) {
        int rr = gr0 + mt * 16 + q4 * 4 + e;
        float v = C[mt][nt][e];
        if (MODE == 0) v += bc;
        if (MODE == 1) v += bm[mt][e];
        if (MODE == 2) v = fmaxf(v + bc, 0.0f);
        if (MODE == 3) v = 1.0f / (1.0f + __expf(-v)) + bc;
        if (MODE == 3)
          ((float*)Cout)[(long)g * cStride + (long)rr * Nb + cc] = v;
        else
          ((u16*)Cout)[(long)g * cStride + (long)rr * Nb + cc] = f2bf(v);
      }
    }
  }
}

// ---------------- fused flash attention (one qkv block per WG) ----------------
// grid (32, gc): x = 128-row tile, y = qkv block within chunk.
// softmax(sigmoid(QK^T/16)) @ V, accumulated (x 1/200) into acc via atomics.
// Row sums come free via an appended ones-column on V^T (17th n-tile).
__global__ __launch_bounds__(256, 2) void attn(const u16* __restrict__ qkv,
                                               float* __restrict__ acc) {
  __shared__ __align__(16) u16 lds[33792];
  u16* Kl = lds;          // [64][256] (32 16B-blocks/row, swizzled)
  u16* Pl = lds;          // [128][64] aliases Kl after S-phase
  u16* Vl = lds + 16384;  // [272][64] rows 256..271 = aug (ones/zeros)

  const int tid = threadIdx.x;
  const int lane = tid & 63, w = tid >> 6;
  const int l15 = lane & 15, q4 = lane >> 4;
  const long slot = 3145728L * blockIdx.y;
  const u16* Qg = qkv + slot;
  const u16* Kg = qkv + slot + 1048576;
  const u16* Vg = qkv + slot + 2097152;
  const int rw = blockIdx.x * 128 + w * 32;

  // aug rows of V^T: row 256 = 1.0, rows 257..271 = 0 (swizzle-invariant: row-constant)
  for (int i = tid; i < 1024; i += 256) {
    int rr = i >> 6, c = i & 63;
    Vl[(256 + rr) * 64 + c] = (rr == 0) ? (u16)0x3F80 : (u16)0;
  }

  // cache Q fragments in registers: 2 m-tiles x 8 k-steps
  s16x8 qf[2][8];
#pragma unroll
  for (int mt = 0; mt < 2; ++mt) {
    const u16* qr = Qg + (long)(rw + mt * 16 + l15) * 256 + q4 * 8;
#pragma unroll
    for (int ks = 0; ks < 8; ++ks) qf[mt][ks] = *(const s16x8*)(qr + ks * 32);
  }

  f32x4 O[2][17];
#pragma unroll
  for (int mt = 0; mt < 2; ++mt)
#pragma unroll
    for (int nt = 0; nt < 17; ++nt) O[mt][nt] = (f32x4)0.0f;

  for (int jt = 0; jt < 64; ++jt) {
    const int j0 = jt << 6;
    __syncthreads();  // prior PV reads of Pl/Vl done before restaging
#pragma unroll
    for (int i = 0; i < 8; ++i) {  // K-tile: 2048 16B blocks
      int s = tid + i * 256;
      int r = s >> 5, p = s & 31;
      async_cp16(Kg + (long)(j0 + r) * 256 + ((p ^ (r & 7)) << 3), Kl + s * 8);
    }
#pragma unroll
    for (int i = 0; i < 8; ++i) {  // V^T-tile: 2048 16B blocks
      int s = tid + i * 256;
      int r = s >> 3, p = s & 7;
      async_cp16(Vg + (long)r * 4096 + j0 + ((p ^ (r & 7)) << 3), Vl + s * 8);
    }
    __syncthreads();

    // S = Q K^T
    f32x4 S[2][4];
#pragma unroll
    for (int mt = 0; mt < 2; ++mt)
#pragma unroll
      for (int nt = 0; nt < 4; ++nt) S[mt][nt] = (f32x4)0.0f;
#pragma unroll
    for (int ks = 0; ks < 8; ++ks) {
#pragma unroll
      for (int nt = 0; nt < 4; ++nt) {
        int kr = nt * 16 + l15;
        int kb = ks * 4 + q4;
        s16x8 b = *(const s16x8*)(Kl + kr * 256 + ((kb ^ (kr & 7)) << 3));
        S[0][nt] = MFMA16(qf[0][ks], b, S[0][nt]);
        S[1][nt] = MFMA16(qf[1][ks], b, S[1][nt]);
      }
    }
    __syncthreads();  // all waves done reading Kl

    // P = exp(sigmoid(S/16)) -> bf16 into Pl (over Kl region)
#pragma unroll
    for (int mt = 0; mt < 2; ++mt)
#pragma unroll
      for (int nt = 0; nt < 4; ++nt)
#pragma unroll
        for (int e = 0; e < 4; ++e) {
          float sv = S[mt][nt][e] * 0.0625f;
          float p = __expf(__builtin_amdgcn_rcpf(1.0f + __expf(-sv)));
          int pr = w * 32 + mt * 16 + q4 * 4 + e;
          int pc = nt * 16 + l15;
          Pl[pr * 64 + (((pc >> 3) ^ (pr & 7)) << 3) + (pc & 7)] = f2bf(p);
        }
    __syncthreads();

    // O += P V  (17th n-tile accumulates row sums)
#pragma unroll
    for (int ks = 0; ks < 2; ++ks) {
      int kb = ks * 4 + q4;
      int pr0 = w * 32 + l15;
      s16x8 a0 = *(const s16x8*)(Pl + pr0 * 64 + ((kb ^ (pr0 & 7)) << 3));
      int pr1 = pr0 + 16;
      s16x8 a1 = *(const s16x8*)(Pl + pr1 * 64 + ((kb ^ (pr1 & 7)) << 3));
#pragma unroll
      for (int nt = 0; nt < 17; ++nt) {
        int vr = nt * 16 + l15;
        s16x8 b = *(const s16x8*)(Vl + vr * 64 + ((kb ^ (vr & 7)) << 3));
        O[0][nt] = MFMA16(a0, b, O[0][nt]);
        O[1][nt] = MFMA16(a1, b, O[1][nt]);
      }
    }
  }

  // normalize by row sums, accumulate (x 1/200)
#pragma unroll
  for (int mt = 0; mt < 2; ++mt) {
    float rls[4];
#pragma unroll
    for (int e = 0; e < 4; ++e) {
      float lsum = __shfl(O[mt][16][e], lane & 48, 64);  // col 0 of aug tile holds sum
      rls[e] = 0.005f / lsum;
    }
#pragma unroll
    for (int nt = 0; nt < 16; ++nt) {
#pragma unroll
      for (int e = 0; e < 4; ++e) {
        int rr = rw + mt * 16 + q4 * 4 + e;
        int cc = nt * 16 + l15;
        unsafeAtomicAdd(acc + (long)rr * 256 + cc, O[mt][nt][e] * rls[e]);
      }
    }
  }
}

// ---------------- host ----------------
extern "C" void kernel_launch(void* const* d_in, const int* in_sizes, int n_in,
                              void* d_out, int out_size, void* d_ws, size_t ws_size,
                              hipStream_t stream) {
  const float* x = (const float*)d_in[0];
  const float* Wq = (const float*)d_in[1];
  const float* bq = (const float*)d_in[2];
  const float* Wk = (const float*)d_in[3];
  const float* bk = (const float*)d_in[4];
  const float* Wv = (const float*)d_in[5];
  const float* bv = (const float*)d_in[6];
  const float* Wl = (const float*)d_in[7];
  const float* bl = (const float*)d_in[8];
  const float* fw = (const float*)d_in[9];
  const float* fb = (const float*)d_in[10];
  float* out = (float*)d_out;

  u16* wsb = (u16*)d_ws;
  u16* xb = wsb;                    // 1,048,576
  u16* wqb = wsb + 1048576;         // 13,107,200
  u16* wkb = wqb + 13107200;
  u16* wvb = wkb + 13107200;
  u16* wlb = wvb + 13107200;        // 1,310,720
  u16* fwtb = wlb + 1310720;        // 65,536
  u16* h0 = fwtb + 65536;           // 1,048,576
  u16* h1 = h0 + 1048576;
  u16* qkvb = h1 + 1048576;         // G * 3,145,728 elems

  long fixedBytes = (long)((char*)qkvb - (char*)wsb);
  long avail = (long)ws_size - fixedBytes;
  int G = (int)(avail / 6291456L);
  if (G < 1) G = 1;
  if (G > 200) G = 200;

  hipMemsetAsync(d_out, 0, (size_t)out_size * sizeof(float), stream);

  cvt4<<<dim3(1024), 256, 0, stream>>>(x, xb, 262144);
  cvt4<<<dim3(12800), 256, 0, stream>>>(Wq, wqb, 3276800);
  cvt4<<<dim3(12800), 256, 0, stream>>>(Wk, wkb, 3276800);
  cvt4<<<dim3(12800), 256, 0, stream>>>(Wv, wvb, 3276800);
  cvt4<<<dim3(1280), 256, 0, stream>>>(Wl, wlb, 327680);
  cvt_t<<<dim3(256), 256, 0, stream>>>(fw, fwtb);

  for (int c0 = 0; c0 < 200; c0 += G) {
    int gc = (200 - c0 < G) ? (200 - c0) : G;
    // Q, K: [4096][256] = x @ W^T + b
    gemm_bt<0><<<dim3(64, gc), 256, 0, stream>>>(xb, wqb + (long)c0 * 65536, qkvb,
                                                 bq + (long)c0 * 256, 4096, 256,
                                                 0L, 65536L, 3145728L, 256L);
    gemm_bt<0><<<dim3(64, gc), 256, 0, stream>>>(xb, wkb + (long)c0 * 65536, qkvb + 1048576,
                                                 bk + (long)c0 * 256, 4096, 256,
                                                 0L, 65536L, 3145728L, 256L);
    // V^T: [256][4096] = Wv @ x^T (+bv per row) -- same kernel, swapped operands
    gemm_bt<1><<<dim3(64, gc), 256, 0, stream>>>(wvb + (long)c0 * 65536, xb, qkvb + 2097152,
                                                 bv + (long)c0 * 256, 256, 4096,
                                                 65536L, 0L, 3145728L, 256L);
    attn<<<dim3(32, gc), 256, 0, stream>>>(qkvb, out);
  }

  // MLP: h0 = bf16(acc); 20 x relu-GEMM ping-pong; final sigmoid head
  cvt4<<<dim3(1024), 256, 0, stream>>>(out, h0, 262144);
  for (int i = 0; i < 20; ++i) {
    u16* hin = (i & 1) ? h1 : h0;
    u16* hout = (i & 1) ? h0 : h1;
    gemm_bt<2><<<dim3(64, 1), 256, 0, stream>>>(hin, wlb + (long)i * 65536, hout,
                                                bl + (long)i * 256, 4096, 256, 0L, 0L, 0L, 0L);
  }
  gemm_bt<3><<<dim3(64, 1), 256, 0, stream>>>(h0, fwtb, d_out, fb, 4096, 256, 0L, 0L, 0L, 0L);
}

// Round 2
// 6554.967 us; speedup vs baseline: 2.5660x; 2.5660x over previous
//
#include <hip/hip_runtime.h>

typedef unsigned short u16;
typedef __attribute__((ext_vector_type(8))) short s16x8;
typedef __attribute__((ext_vector_type(4))) short s16x4;
typedef __attribute__((ext_vector_type(4))) float f32x4;

#define MFMA16(a, b, c) __builtin_amdgcn_mfma_f32_16x16x32_bf16(a, b, c, 0, 0, 0)

__device__ __forceinline__ u16 f2bf(float f) {
  unsigned u = __float_as_uint(f);
  u += 0x7FFFu + ((u >> 16) & 1u);
  return (u16)(u >> 16);
}

// async 16B global->LDS. LDS side is wave-uniform base + lane*16.
__device__ __forceinline__ void async_cp16(const u16* g, u16* l) {
  __builtin_amdgcn_global_load_lds(
      (__attribute__((address_space(1))) void*)g,
      (__attribute__((address_space(3))) void*)l,
      16, 0, 0);
}

// ---------------- conversion kernels ----------------
__global__ void cvt4(const float* __restrict__ s, u16* __restrict__ d, int n4) {
  int i = blockIdx.x * 256 + threadIdx.x;
  if (i >= n4) return;
  f32x4 v = *(const f32x4*)(s + 4L * i);
  s16x4 o;
  o[0] = (short)f2bf(v[0]); o[1] = (short)f2bf(v[1]);
  o[2] = (short)f2bf(v[2]); o[3] = (short)f2bf(v[3]);
  *(s16x4*)(d + 4L * i) = o;
}

// final_weight [256][256] fp32 -> transposed bf16 (fwT[j][k] = fw[k][j])
__global__ void cvt_t(const float* __restrict__ s, u16* __restrict__ d) {
  int j = blockIdx.x, k = threadIdx.x;
  d[j * 256 + k] = f2bf(s[k * 256 + j]);
}

// ---------------- unified BT-GEMM ----------------
// C[i][j] = sum_k A[i][k] * B[j][k]  (+bias, activation per MODE). K=256.
// MODE 0: +bias[col] -> bf16 | 1: +bias[row] -> bf16 | 2: relu -> bf16 | 3: sigmoid+bias -> fp32
template <int MODE>
__global__ __launch_bounds__(256, 4) void gemm_bt(
    const u16* __restrict__ A, const u16* __restrict__ B, void* __restrict__ Cout,
    const float* __restrict__ bias, int Ma, int Nb,
    long aStride, long bStride, long cStride, long biasStride) {
  __shared__ __align__(16) u16 lds[16384];
  const int tid = threadIdx.x;
  const int lane = tid & 63;
  const int l15 = lane & 15, q4 = lane >> 4;
  const int w = tid >> 6;
  const int qm = w >> 1, qn = w & 1;
  const int g = blockIdx.y;
  A += (long)g * aStride;
  B += (long)g * bStride;
  bias += (long)g * biasStride;
  const int tiles_n = Nb >> 7;
  const int tm = blockIdx.x / tiles_n, tn = blockIdx.x % tiles_n;
  const int row0 = tm << 7, col0 = tn << 7;

  f32x4 C[4][4];
#pragma unroll
  for (int i = 0; i < 4; ++i)
#pragma unroll
    for (int j = 0; j < 4; ++j) C[i][j] = (f32x4)0.0f;

  u16* Al = lds;
  u16* Bl = lds + 8192;

  for (int kc = 0; kc < 4; ++kc) {
    __syncthreads();
#pragma unroll
    for (int i = 0; i < 4; ++i) {
      int s = tid + i * 256;
      int r = s >> 3, p = s & 7;
      async_cp16(A + (long)(row0 + r) * 256 + kc * 64 + ((p ^ (r & 7)) << 3), Al + s * 8);
    }
#pragma unroll
    for (int i = 0; i < 4; ++i) {
      int s = tid + i * 256;
      int r = s >> 3, p = s & 7;
      async_cp16(B + (long)(col0 + r) * 256 + kc * 64 + ((p ^ (r & 7)) << 3), Bl + s * 8);
    }
    __syncthreads();
#pragma unroll
    for (int ks = 0; ks < 2; ++ks) {
      s16x8 a[4];
#pragma unroll
      for (int mt = 0; mt < 4; ++mt) {
        int r = qm * 64 + mt * 16 + l15;
        int kb = ks * 4 + q4;
        a[mt] = *(const s16x8*)(Al + r * 64 + ((kb ^ (r & 7)) << 3));
      }
#pragma unroll
      for (int nt = 0; nt < 4; ++nt) {
        int rn = qn * 64 + nt * 16 + l15;
        int kb = ks * 4 + q4;
        s16x8 b = *(const s16x8*)(Bl + rn * 64 + ((kb ^ (rn & 7)) << 3));
#pragma unroll
        for (int mt = 0; mt < 4; ++mt) C[mt][nt] = MFMA16(a[mt], b, C[mt][nt]);
      }
    }
  }

  const int gr0 = row0 + qm * 64, gc0 = col0 + qn * 64;
  float bm[4][4];
  if (MODE == 1) {
#pragma unroll
    for (int mt = 0; mt < 4; ++mt)
#pragma unroll
      for (int e = 0; e < 4; ++e) bm[mt][e] = bias[gr0 + mt * 16 + q4 * 4 + e];
  }
#pragma unroll
  for (int nt = 0; nt < 4; ++nt) {
    int cc = gc0 + nt * 16 + l15;
    float bc = (MODE != 1) ? bias[cc] : 0.0f;
#pragma unroll
    for (int mt = 0; mt < 4; ++mt) {
#pragma unroll
      for (int e = 0; e < 4; ++e) {
        int rr = gr0 + mt * 16 + q4 * 4 + e;
        float v = C[mt][nt][e];
        if (MODE == 0) v += bc;
        if (MODE == 1) v += bm[mt][e];
        if (MODE == 2) v = fmaxf(v + bc, 0.0f);
        if (MODE == 3) v = 1.0f / (1.0f + __expf(-v)) + bc;
        if (MODE == 3)
          ((float*)Cout)[(long)g * cStride + (long)rr * Nb + cc] = v;
        else
          ((u16*)Cout)[(long)g * cStride + (long)rr * Nb + cc] = f2bf(v);
      }
    }
  }
}

// ---------------- fused flash attention ----------------
// One qkv block = 32 row-tile WGs, clustered on one XCD (f&7) for L2 K/V reuse.
// Nk=32 key tile, LDS double-buffered via global_load_lds issued one iteration
// ahead; P in a private padded buffer (per-wave rows) -> ONE barrier per iter.
__global__ __launch_bounds__(256, 2) void attn(const u16* __restrict__ qkv,
                                               float* __restrict__ acc, int gc, int swiz) {
  // K0/K1: [32][256] (16KB each, XOR-swizzled 16B blocks)
  // V0/V1: [256][32] block-column-major: addr(vr,k) = (vr + 256*(k>>3))*8 + (k&7)
  // Pl: [128][40] bf16 (stride 40: conflict-free, 16B-aligned rows)
  // Va: [16][40] aug tile (row 0 = ones)
  __shared__ __align__(16) u16 lds[38528];
  u16* K0 = lds;
  u16* K1 = lds + 8192;
  u16* V0 = lds + 16384;
  u16* V1 = lds + 24576;
  u16* Pl = lds + 32768;
  u16* Va = lds + 37888;

  const int f = blockIdx.x;
  int b, tile;
  if (swiz) { b = (f & 7) + ((f >> 8) << 3); tile = (f >> 3) & 31; }
  else { b = f >> 5; tile = f & 31; }
  if (b >= gc) return;

  const int tid = threadIdx.x;
  const int lane = tid & 63, w = tid >> 6;
  const int l15 = lane & 15, q4 = lane >> 4;
  const long slot = 3145728L * b;
  const u16* Qg = qkv + slot;
  const u16* Kg = qkv + slot + 1048576;
  const u16* Vg = qkv + slot + 2097152;
  const int rw = tile * 128 + w * 32;

  // aug tile: row 0 = 1.0, rows 1..15 = 0
  for (int i = tid; i < 640; i += 256) Va[i] = (i < 40) ? (u16)0x3F80 : (u16)0;

  // Q fragments in registers: 2 m-tiles x 8 k-slabs
  s16x8 qf[2][8];
#pragma unroll
  for (int mt = 0; mt < 2; ++mt) {
    const u16* qr = Qg + (long)(rw + mt * 16 + l15) * 256 + q4 * 8;
#pragma unroll
    for (int ks = 0; ks < 8; ++ks) qf[mt][ks] = *(const s16x8*)(qr + ks * 32);
  }

  f32x4 O[2][17];
#pragma unroll
  for (int mt = 0; mt < 2; ++mt)
#pragma unroll
    for (int nt = 0; nt < 17; ++nt) O[mt][nt] = (f32x4)0.0f;

  // stage tile jt=0 into buffer 0
  {
#pragma unroll
    for (int i = 0; i < 4; ++i) {
      int s = tid + i * 256;
      int r = s >> 5, p = s & 31;
      async_cp16(Kg + r * 256 + ((p ^ (r & 7)) << 3), K0 + s * 8);
    }
#pragma unroll
    for (int i = 0; i < 4; ++i)
      async_cp16(Vg + (long)tid * 4096 + i * 8, V0 + (i * 256 + tid) * 8);
  }

  for (int jt = 0; jt < 128; ++jt) {
    u16* Kc = (jt & 1) ? K1 : K0;
    u16* Vc = (jt & 1) ? V1 : V0;
    __syncthreads();  // drains iteration-old DMA; all waves done with prev buffers

    if (jt < 127) {  // stage jt+1 into the other buffer (in flight during compute)
      const u16* Kg2 = Kg + (jt + 1) * 8192;
      const u16* Vg2 = Vg + (jt + 1) * 32;
      u16* Kd = (jt & 1) ? K0 : K1;
      u16* Vd = (jt & 1) ? V0 : V1;
#pragma unroll
      for (int i = 0; i < 4; ++i) {
        int s = tid + i * 256;
        int r = s >> 5, p = s & 31;
        async_cp16(Kg2 + r * 256 + ((p ^ (r & 7)) << 3), Kd + s * 8);
      }
#pragma unroll
      for (int i = 0; i < 4; ++i)
        async_cp16(Vg2 + (long)tid * 4096 + i * 8, Vd + (i * 256 + tid) * 8);
    }

    // S = Q K^T for 32 keys
    f32x4 S[2][2];
    S[0][0] = (f32x4)0.0f; S[0][1] = (f32x4)0.0f;
    S[1][0] = (f32x4)0.0f; S[1][1] = (f32x4)0.0f;
#pragma unroll
    for (int ks = 0; ks < 8; ++ks) {
#pragma unroll
      for (int nt = 0; nt < 2; ++nt) {
        int kr = nt * 16 + l15;
        int kb = ks * 4 + q4;
        s16x8 bfr = *(const s16x8*)(Kc + kr * 256 + ((kb ^ (kr & 7)) << 3));
        S[0][nt] = MFMA16(qf[0][ks], bfr, S[0][nt]);
        S[1][nt] = MFMA16(qf[1][ks], bfr, S[1][nt]);
      }
    }

    // P = exp(sigmoid(S/16)) -> private P buffer (per-wave rows; no barrier needed)
#pragma unroll
    for (int mt = 0; mt < 2; ++mt)
#pragma unroll
      for (int nt = 0; nt < 2; ++nt)
#pragma unroll
        for (int e = 0; e < 4; ++e) {
          float sv = S[mt][nt][e] * 0.0625f;
          float p = __expf(__builtin_amdgcn_rcpf(1.0f + __expf(-sv)));
          int pr = w * 32 + mt * 16 + q4 * 4 + e;
          Pl[pr * 40 + nt * 16 + l15] = f2bf(p);
        }

    // O += P V (17th n-tile = row sums via aug ones)
    {
      int pr0 = w * 32 + l15;
      s16x8 a0 = *(const s16x8*)(Pl + pr0 * 40 + q4 * 8);
      s16x8 a1 = *(const s16x8*)(Pl + (pr0 + 16) * 40 + q4 * 8);
#pragma unroll
      for (int nt = 0; nt < 16; ++nt) {
        int vr = nt * 16 + l15;
        s16x8 bfr = *(const s16x8*)(Vc + (vr + (q4 << 8)) * 8);
        O[0][nt] = MFMA16(a0, bfr, O[0][nt]);
        O[1][nt] = MFMA16(a1, bfr, O[1][nt]);
      }
      s16x8 bA = *(const s16x8*)(Va + l15 * 40 + q4 * 8);
      O[0][16] = MFMA16(a0, bA, O[0][16]);
      O[1][16] = MFMA16(a1, bA, O[1][16]);
    }
  }

  // normalize by row sums, accumulate (x 1/200)
#pragma unroll
  for (int mt = 0; mt < 2; ++mt) {
    float rls[4];
#pragma unroll
    for (int e = 0; e < 4; ++e) {
      float lsum = __shfl(O[mt][16][e], lane & 48, 64);  // col 0 of aug tile
      rls[e] = 0.005f / lsum;
    }
#pragma unroll
    for (int nt = 0; nt < 16; ++nt) {
#pragma unroll
      for (int e = 0; e < 4; ++e) {
        int rr = rw + mt * 16 + q4 * 4 + e;
        int cc = nt * 16 + l15;
        unsafeAtomicAdd(acc + (long)rr * 256 + cc, O[mt][nt][e] * rls[e]);
      }
    }
  }
}

// ---------------- host ----------------
extern "C" void kernel_launch(void* const* d_in, const int* in_sizes, int n_in,
                              void* d_out, int out_size, void* d_ws, size_t ws_size,
                              hipStream_t stream) {
  const float* x = (const float*)d_in[0];
  const float* Wq = (const float*)d_in[1];
  const float* bq = (const float*)d_in[2];
  const float* Wk = (const float*)d_in[3];
  const float* bk = (const float*)d_in[4];
  const float* Wv = (const float*)d_in[5];
  const float* bv = (const float*)d_in[6];
  const float* Wl = (const float*)d_in[7];
  const float* bl = (const float*)d_in[8];
  const float* fw = (const float*)d_in[9];
  const float* fb = (const float*)d_in[10];
  float* out = (float*)d_out;

  u16* wsb = (u16*)d_ws;
  u16* xb = wsb;                    // 1,048,576
  u16* wqb = wsb + 1048576;         // 13,107,200
  u16* wkb = wqb + 13107200;
  u16* wvb = wkb + 13107200;
  u16* wlb = wvb + 13107200;        // 1,310,720
  u16* fwtb = wlb + 1310720;        // 65,536
  u16* h0 = fwtb + 65536;           // 1,048,576
  u16* h1 = h0 + 1048576;
  u16* qkvb = h1 + 1048576;         // G * 3,145,728 elems

  long fixedBytes = (long)((char*)qkvb - (char*)wsb);
  long avail = (long)ws_size - fixedBytes;
  int G = (int)(avail / 6291456L);
  if (G > 24) G = 24;
  if (G >= 8) G &= ~7;  // multiple of 8 for XCD clustering
  if (G < 1) G = 1;

  hipMemsetAsync(d_out, 0, (size_t)out_size * sizeof(float), stream);

  cvt4<<<dim3(1024), 256, 0, stream>>>(x, xb, 262144);
  cvt4<<<dim3(12800), 256, 0, stream>>>(Wq, wqb, 3276800);
  cvt4<<<dim3(12800), 256, 0, stream>>>(Wk, wkb, 3276800);
  cvt4<<<dim3(12800), 256, 0, stream>>>(Wv, wvb, 3276800);
  cvt4<<<dim3(1280), 256, 0, stream>>>(Wl, wlb, 327680);
  cvt_t<<<dim3(256), 256, 0, stream>>>(fw, fwtb);

  for (int c0 = 0; c0 < 200; c0 += G) {
    int gc = (200 - c0 < G) ? (200 - c0) : G;
    gemm_bt<0><<<dim3(64, gc), 256, 0, stream>>>(xb, wqb + (long)c0 * 65536, qkvb,
                                                 bq + (long)c0 * 256, 4096, 256,
                                                 0L, 65536L, 3145728L, 256L);
    gemm_bt<0><<<dim3(64, gc), 256, 0, stream>>>(xb, wkb + (long)c0 * 65536, qkvb + 1048576,
                                                 bk + (long)c0 * 256, 4096, 256,
                                                 0L, 65536L, 3145728L, 256L);
    gemm_bt<1><<<dim3(64, gc), 256, 0, stream>>>(wvb + (long)c0 * 65536, xb, qkvb + 2097152,
                                                 bv + (long)c0 * 256, 256, 4096,
                                                 65536L, 0L, 3145728L, 256L);
    int swiz = (gc % 8 == 0) ? 1 : 0;
    attn<<<dim3(32 * gc), 256, 0, stream>>>(qkvb, out, gc, swiz);
  }

  // MLP: h0 = bf16(acc); 20 x relu-GEMM ping-pong; final sigmoid head
  cvt4<<<dim3(1024), 256, 0, stream>>>(out, h0, 262144);
  for (int i = 0; i < 20; ++i) {
    u16* hin = (i & 1) ? h1 : h0;
    u16* hout = (i & 1) ? h0 : h1;
    gemm_bt<2><<<dim3(64, 1), 256, 0, stream>>>(hin, wlb + (long)i * 65536, hout,
                                                bl + (long)i * 256, 4096, 256, 0L, 0L, 0L, 0L);
  }
  gemm_bt<3><<<dim3(64, 1), 256, 0, stream>>>(h0, fwtb, d_out, fb, 4096, 256, 0L, 0L, 0L, 0L);
}

// Round 3
// 5252.130 us; speedup vs baseline: 3.2026x; 1.2481x over previous
//
#include <hip/hip_runtime.h>

typedef unsigned short u16;
typedef __attribute__((ext_vector_type(8))) short s16x8;
typedef __attribute__((ext_vector_type(4))) short s16x4;
typedef __attribute__((ext_vector_type(4))) float f32x4;

#define MFMA16(a, b, c) __builtin_amdgcn_mfma_f32_16x16x32_bf16(a, b, c, 0, 0, 0)

__device__ __forceinline__ u16 f2bf(float f) {
  unsigned u = __float_as_uint(f);
  u += 0x7FFFu + ((u >> 16) & 1u);
  return (u16)(u >> 16);
}

// async 16B global->LDS. LDS dest is wave-uniform base + lane*16.
__device__ __forceinline__ void async_cp16(const u16* g, u16* l) {
  __builtin_amdgcn_global_load_lds(
      (__attribute__((address_space(1))) void*)g,
      (__attribute__((address_space(3))) void*)l,
      16, 0, 0);
}

// ---------------- conversion kernels ----------------
__global__ void cvt4(const float* __restrict__ s, u16* __restrict__ d, int n4) {
  int i = blockIdx.x * 256 + threadIdx.x;
  if (i >= n4) return;
  f32x4 v = *(const f32x4*)(s + 4L * i);
  s16x4 o;
  o[0] = (short)f2bf(v[0]); o[1] = (short)f2bf(v[1]);
  o[2] = (short)f2bf(v[2]); o[3] = (short)f2bf(v[3]);
  *(s16x4*)(d + 4L * i) = o;
}

// final_weight [256][256] fp32 -> transposed bf16
__global__ void cvt_t(const float* __restrict__ s, u16* __restrict__ d) {
  int j = blockIdx.x, k = threadIdx.x;
  d[j * 256 + k] = f2bf(s[k * 256 + j]);
}

// ---------------- fused QKV projection GEMM ----------------
// grid (64, gc, 3). z=0: Q=(x@Wq^T+bq)/16 row-major. z=1: K=x@Wk^T+bk row-major.
// z=2: V^T=Wv@x^T (+bv per dim row), written PRE-TILED in attn's LDS layout:
//      tile jt (32 keys): addr = jt*8192 + (dim + 256*((k&31)>>3))*8 + (k&7)
__global__ __launch_bounds__(256, 4) void gemm_qkv(
    const u16* __restrict__ xb, const u16* __restrict__ wq, const u16* __restrict__ wk,
    const u16* __restrict__ wv, const float* __restrict__ bqv,
    const float* __restrict__ bkv, const float* __restrict__ bvv,
    u16* __restrict__ qkv, int c0) {
  __shared__ __align__(16) u16 lds[16384];
  const int z = blockIdx.z, g = blockIdx.y;
  const u16* A; const u16* B; const float* bias; u16* out;
  int tiles_n, Nb;
  if (z == 0)      { A = xb; B = wq + (long)(c0 + g) * 65536; bias = bqv + (long)(c0 + g) * 256;
                     out = qkv + (long)g * 3145728;           tiles_n = 2;  Nb = 256; }
  else if (z == 1) { A = xb; B = wk + (long)(c0 + g) * 65536; bias = bkv + (long)(c0 + g) * 256;
                     out = qkv + (long)g * 3145728 + 1048576; tiles_n = 2;  Nb = 256; }
  else             { A = wv + (long)(c0 + g) * 65536; B = xb; bias = bvv + (long)(c0 + g) * 256;
                     out = qkv + (long)g * 3145728 + 2097152; tiles_n = 32; Nb = 4096; }

  const int tid = threadIdx.x;
  const int lane = tid & 63;
  const int l15 = lane & 15, q4 = lane >> 4;
  const int w = tid >> 6;
  const int qm = w >> 1, qn = w & 1;
  const int tm = blockIdx.x / tiles_n, tn = blockIdx.x % tiles_n;
  const int row0 = tm << 7, col0 = tn << 7;

  f32x4 C[4][4];
#pragma unroll
  for (int i = 0; i < 4; ++i)
#pragma unroll
    for (int j = 0; j < 4; ++j) C[i][j] = (f32x4)0.0f;

  u16* Al = lds;
  u16* Bl = lds + 8192;

  for (int kc = 0; kc < 4; ++kc) {
    __syncthreads();
#pragma unroll
    for (int i = 0; i < 4; ++i) {
      int s = tid + i * 256;
      int r = s >> 3, p = s & 7;
      async_cp16(A + (long)(row0 + r) * 256 + kc * 64 + ((p ^ (r & 7)) << 3), Al + s * 8);
    }
#pragma unroll
    for (int i = 0; i < 4; ++i) {
      int s = tid + i * 256;
      int r = s >> 3, p = s & 7;
      async_cp16(B + (long)(col0 + r) * 256 + kc * 64 + ((p ^ (r & 7)) << 3), Bl + s * 8);
    }
    __syncthreads();
#pragma unroll
    for (int ks = 0; ks < 2; ++ks) {
      s16x8 a[4];
#pragma unroll
      for (int mt = 0; mt < 4; ++mt) {
        int r = qm * 64 + mt * 16 + l15;
        int kb = ks * 4 + q4;
        a[mt] = *(const s16x8*)(Al + r * 64 + ((kb ^ (r & 7)) << 3));
      }
#pragma unroll
      for (int nt = 0; nt < 4; ++nt) {
        int rn = qn * 64 + nt * 16 + l15;
        int kb = ks * 4 + q4;
        s16x8 b = *(const s16x8*)(Bl + rn * 64 + ((kb ^ (rn & 7)) << 3));
#pragma unroll
        for (int mt = 0; mt < 4; ++mt) C[mt][nt] = MFMA16(a[mt], b, C[mt][nt]);
      }
    }
  }

  const int gr0 = row0 + qm * 64, gc0 = col0 + qn * 64;
  if (z < 2) {
    const float sc = (z == 0) ? 0.0625f : 1.0f;
#pragma unroll
    for (int nt = 0; nt < 4; ++nt) {
      int cc = gc0 + nt * 16 + l15;
      float bc = bias[cc];
#pragma unroll
      for (int mt = 0; mt < 4; ++mt)
#pragma unroll
        for (int e = 0; e < 4; ++e) {
          int rr = gr0 + mt * 16 + q4 * 4 + e;
          out[(long)rr * 256 + cc] = f2bf((C[mt][nt][e] + bc) * sc);
        }
    }
  } else {
    float bm[4][4];
#pragma unroll
    for (int mt = 0; mt < 4; ++mt)
#pragma unroll
      for (int e = 0; e < 4; ++e) bm[mt][e] = bias[gr0 + mt * 16 + q4 * 4 + e];
#pragma unroll
    for (int nt = 0; nt < 4; ++nt) {
      int cc = gc0 + nt * 16 + l15;
#pragma unroll
      for (int mt = 0; mt < 4; ++mt)
#pragma unroll
        for (int e = 0; e < 4; ++e) {
          int rr = gr0 + mt * 16 + q4 * 4 + e;  // dim
          long ad = (long)(cc >> 5) * 8192 + ((cc >> 3) & 3) * 2048 + rr * 8 + (cc & 7);
          out[ad] = f2bf(C[mt][nt][e] + bm[mt][e]);
        }
    }
  }
}

// ---------------- MLP / final GEMM ----------------
// MODE 2: relu(x@W^T+b) -> bf16 ; MODE 3: sigmoid(x@Wt)+b -> fp32
template <int MODE>
__global__ __launch_bounds__(256, 4) void gemm_bt(
    const u16* __restrict__ A, const u16* __restrict__ B, void* __restrict__ Cout,
    const float* __restrict__ bias) {
  __shared__ __align__(16) u16 lds[16384];
  const int tid = threadIdx.x;
  const int lane = tid & 63;
  const int l15 = lane & 15, q4 = lane >> 4;
  const int w = tid >> 6;
  const int qm = w >> 1, qn = w & 1;
  const int tm = blockIdx.x >> 1, tn = blockIdx.x & 1;
  const int row0 = tm << 7, col0 = tn << 7;

  f32x4 C[4][4];
#pragma unroll
  for (int i = 0; i < 4; ++i)
#pragma unroll
    for (int j = 0; j < 4; ++j) C[i][j] = (f32x4)0.0f;

  u16* Al = lds;
  u16* Bl = lds + 8192;

  for (int kc = 0; kc < 4; ++kc) {
    __syncthreads();
#pragma unroll
    for (int i = 0; i < 4; ++i) {
      int s = tid + i * 256;
      int r = s >> 3, p = s & 7;
      async_cp16(A + (long)(row0 + r) * 256 + kc * 64 + ((p ^ (r & 7)) << 3), Al + s * 8);
    }
#pragma unroll
    for (int i = 0; i < 4; ++i) {
      int s = tid + i * 256;
      int r = s >> 3, p = s & 7;
      async_cp16(B + (long)(col0 + r) * 256 + kc * 64 + ((p ^ (r & 7)) << 3), Bl + s * 8);
    }
    __syncthreads();
#pragma unroll
    for (int ks = 0; ks < 2; ++ks) {
      s16x8 a[4];
#pragma unroll
      for (int mt = 0; mt < 4; ++mt) {
        int r = qm * 64 + mt * 16 + l15;
        int kb = ks * 4 + q4;
        a[mt] = *(const s16x8*)(Al + r * 64 + ((kb ^ (r & 7)) << 3));
      }
#pragma unroll
      for (int nt = 0; nt < 4; ++nt) {
        int rn = qn * 64 + nt * 16 + l15;
        int kb = ks * 4 + q4;
        s16x8 b = *(const s16x8*)(Bl + rn * 64 + ((kb ^ (rn & 7)) << 3));
#pragma unroll
        for (int mt = 0; mt < 4; ++mt) C[mt][nt] = MFMA16(a[mt], b, C[mt][nt]);
      }
    }
  }

  const int gr0 = row0 + qm * 64, gc0 = col0 + qn * 64;
#pragma unroll
  for (int nt = 0; nt < 4; ++nt) {
    int cc = gc0 + nt * 16 + l15;
    float bc = bias[cc];
#pragma unroll
    for (int mt = 0; mt < 4; ++mt)
#pragma unroll
      for (int e = 0; e < 4; ++e) {
        int rr = gr0 + mt * 16 + q4 * 4 + e;
        float v = C[mt][nt][e];
        if (MODE == 2) {
          v = fmaxf(v + bc, 0.0f);
          ((u16*)Cout)[(long)rr * 256 + cc] = f2bf(v);
        } else {
          v = 1.0f / (1.0f + __expf(-v)) + bc;
          ((float*)Cout)[(long)rr * 256 + cc] = v;
        }
      }
  }
}

// ---------------- fused flash attention ----------------
// One qkv block = 32 row-tile WGs clustered on one XCD (f&7) for L2 K/V reuse.
// Nk=32, LDS double-buffered, DMA issued one iteration ahead, ONE barrier/iter.
// K LDS layout (kb-major + XOR): addr(key,kb) = (kb>>3)*2048 + key*64 + ((kb&7)^(key&7))*8
// V LDS layout = pre-tiled global layout (identity DMA).
// P: [128][40] bf16. Row sums free via constant ones B-fragment (17th n-tile).
__global__ __launch_bounds__(256, 2) void attn(const u16* __restrict__ qkv,
                                               float* __restrict__ acc, int gc, int swiz) {
  __shared__ __align__(16) u16 lds[37888];  // K0|K1|V0|V1|P
  u16* const Pl = lds + 32768;

  const int f = blockIdx.x;
  int b, tile;
  if (swiz) { b = (f & 7) + ((f >> 8) << 3); tile = (f >> 3) & 31; }
  else { b = f >> 5; tile = f & 31; }
  if (b >= gc) return;

  const int tid = threadIdx.x;
  const int lane = tid & 63, w = tid >> 6;
  const int l15 = lane & 15, q4 = lane >> 4;
  const long slot = 3145728L * b;
  const u16* Qg = qkv + slot;
  const u16* Kg = qkv + slot + 1048576;
  const u16* Vg = qkv + slot + 2097152;
  const int rw = tile * 128 + w * 32;

  // K DMA source pieces (dest = linear; global side carries the XOR swizzle)
  const int krow = tid >> 3;                  // 0..31 key row
  const int ksw = (tid & 7) ^ (krow & 7);
  // per-lane K read bases (u16 units): kb even/odd
  const int kb0 = l15 * 64 + ((q4 ^ (l15 & 7)) << 3);
  const int kb1 = kb0 ^ 32;
  // V read base, P bases
  const int vrb = (l15 + (q4 << 8)) << 3;
  const int pwb = (w * 32 + q4 * 4) * 40 + l15;
  const int pra = (w * 32 + l15) * 40 + q4 * 8;

  // ones B-fragment for the row-sum (aug) n-tile
  union { s16x8 v; short s[8]; } one_u;
#pragma unroll
  for (int i = 0; i < 8; ++i) one_u.s[i] = (l15 == 0) ? (short)0x3F80 : (short)0;
  const s16x8 bA = one_u.v;

  // Q fragments in registers (pre-scaled by 1/16): 2 m-tiles x 8 k-slabs
  s16x8 qf[2][8];
#pragma unroll
  for (int mt = 0; mt < 2; ++mt) {
    const u16* qr = Qg + (long)(rw + mt * 16 + l15) * 256 + q4 * 8;
#pragma unroll
    for (int ks = 0; ks < 8; ++ks) qf[mt][ks] = *(const s16x8*)(qr + ks * 32);
  }

  f32x4 O[2][17];
#pragma unroll
  for (int mt = 0; mt < 2; ++mt)
#pragma unroll
    for (int nt = 0; nt < 17; ++nt) O[mt][nt] = (f32x4)0.0f;

  // stage tile 0 into buffer 0
#pragma unroll
  for (int i = 0; i < 4; ++i)
    async_cp16(Kg + krow * 256 + ((i * 8 + ksw) << 3), lds + (tid + i * 256) * 8);
#pragma unroll
  for (int i = 0; i < 4; ++i)
    async_cp16(Vg + (tid + i * 256) * 8, lds + 16384 + (tid + i * 256) * 8);

  for (int jt = 0; jt < 128; ++jt) {
    const int cb = (jt & 1) << 13;  // 8192-u16 buffer toggle
    const u16* Kc = lds + cb;
    const u16* Vc = lds + 16384 + cb;
    __syncthreads();  // drains iteration-old DMA + P writes

    if (jt < 127) {
      const u16* Kn = Kg + (jt + 1) * 8192;
      const u16* Vn = Vg + (jt + 1) * 8192;
      u16* Kd = lds + (cb ^ 16384);
      u16* Vd = lds + 16384 + (cb ^ 16384);
#pragma unroll
      for (int i = 0; i < 4; ++i)
        async_cp16(Kn + krow * 256 + ((i * 8 + ksw) << 3), Kd + (tid + i * 256) * 8);
#pragma unroll
      for (int i = 0; i < 4; ++i)
        async_cp16(Vn + (tid + i * 256) * 8, Vd + (tid + i * 256) * 8);
    }

    // S = Q K^T (pre-scaled), 32 keys
    f32x4 S[2][2];
    S[0][0] = (f32x4)0.0f; S[0][1] = (f32x4)0.0f;
    S[1][0] = (f32x4)0.0f; S[1][1] = (f32x4)0.0f;
#pragma unroll
    for (int ks = 0; ks < 8; ++ks) {
      const u16* kp = Kc + ((ks & 1) ? kb1 : kb0) + (ks >> 1) * 2048;
#pragma unroll
      for (int nt = 0; nt < 2; ++nt) {
        s16x8 bfr = *(const s16x8*)(kp + nt * 1024);
        S[0][nt] = MFMA16(qf[0][ks], bfr, S[0][nt]);
        S[1][nt] = MFMA16(qf[1][ks], bfr, S[1][nt]);
      }
    }

    // P = exp(sigmoid(S)) -> per-wave-private P rows (no barrier needed)
#pragma unroll
    for (int mt = 0; mt < 2; ++mt)
#pragma unroll
      for (int nt = 0; nt < 2; ++nt)
#pragma unroll
        for (int e = 0; e < 4; ++e) {
          float sv = S[mt][nt][e];
          float p = __expf(__builtin_amdgcn_rcpf(1.0f + __expf(-sv)));
          Pl[pwb + mt * 640 + e * 40 + nt * 16] = f2bf(p);
        }

    // O += P V (17th n-tile = row sums via constant ones frag)
    {
      s16x8 a0 = *(const s16x8*)(Pl + pra);
      s16x8 a1 = *(const s16x8*)(Pl + pra + 640);
#pragma unroll
      for (int nt = 0; nt < 16; ++nt) {
        s16x8 bfr = *(const s16x8*)(Vc + vrb + nt * 128);
        O[0][nt] = MFMA16(a0, bfr, O[0][nt]);
        O[1][nt] = MFMA16(a1, bfr, O[1][nt]);
      }
      O[0][16] = MFMA16(a0, bA, O[0][16]);
      O[1][16] = MFMA16(a1, bA, O[1][16]);
    }
  }

  // normalize by row sums, accumulate (x 1/200)
#pragma unroll
  for (int mt = 0; mt < 2; ++mt) {
    float rls[4];
#pragma unroll
    for (int e = 0; e < 4; ++e) {
      float lsum = __shfl(O[mt][16][e], lane & 48, 64);
      rls[e] = 0.005f / lsum;
    }
#pragma unroll
    for (int nt = 0; nt < 16; ++nt) {
#pragma unroll
      for (int e = 0; e < 4; ++e) {
        int rr = rw + mt * 16 + q4 * 4 + e;
        int cc = nt * 16 + l15;
        unsafeAtomicAdd(acc + (long)rr * 256 + cc, O[mt][nt][e] * rls[e]);
      }
    }
  }
}

// ---------------- host ----------------
extern "C" void kernel_launch(void* const* d_in, const int* in_sizes, int n_in,
                              void* d_out, int out_size, void* d_ws, size_t ws_size,
                              hipStream_t stream) {
  const float* x = (const float*)d_in[0];
  const float* Wq = (const float*)d_in[1];
  const float* bq = (const float*)d_in[2];
  const float* Wk = (const float*)d_in[3];
  const float* bk = (const float*)d_in[4];
  const float* Wv = (const float*)d_in[5];
  const float* bv = (const float*)d_in[6];
  const float* Wl = (const float*)d_in[7];
  const float* bl = (const float*)d_in[8];
  const float* fw = (const float*)d_in[9];
  const float* fb = (const float*)d_in[10];
  float* out = (float*)d_out;

  u16* wsb = (u16*)d_ws;
  u16* xb = wsb;                    // 1,048,576
  u16* wqb = wsb + 1048576;         // 13,107,200
  u16* wkb = wqb + 13107200;
  u16* wvb = wkb + 13107200;
  u16* wlb = wvb + 13107200;        // 1,310,720
  u16* fwtb = wlb + 1310720;        // 65,536
  u16* h0 = fwtb + 65536;           // 1,048,576
  u16* h1 = h0 + 1048576;
  u16* qkvb = h1 + 1048576;         // G * 3,145,728 elems

  long fixedBytes = (long)((char*)qkvb - (char*)wsb);
  long avail = (long)ws_size - fixedBytes;
  int G = (int)(avail / 6291456L);
  if (G > 16) G = 16;  // 16 blocks x 32 tiles = 512 WGs = exactly 2/CU
  if (G < 1) G = 1;

  hipMemsetAsync(d_out, 0, (size_t)out_size * sizeof(float), stream);

  cvt4<<<dim3(1024), 256, 0, stream>>>(x, xb, 262144);
  cvt4<<<dim3(12800), 256, 0, stream>>>(Wq, wqb, 3276800);
  cvt4<<<dim3(12800), 256, 0, stream>>>(Wk, wkb, 3276800);
  cvt4<<<dim3(12800), 256, 0, stream>>>(Wv, wvb, 3276800);
  cvt4<<<dim3(1280), 256, 0, stream>>>(Wl, wlb, 327680);
  cvt_t<<<dim3(256), 256, 0, stream>>>(fw, fwtb);

  for (int c0 = 0; c0 < 200; c0 += G) {
    int gc = (200 - c0 < G) ? (200 - c0) : G;
    gemm_qkv<<<dim3(64, gc, 3), 256, 0, stream>>>(xb, wqb, wkb, wvb, bq, bk, bv, qkvb, c0);
    int swiz = (gc == 16 || gc == 8) ? 1 : 0;
    attn<<<dim3(32 * gc), 256, 0, stream>>>(qkvb, out, gc, swiz);
  }

  // MLP: h0 = bf16(acc); 20 x relu-GEMM ping-pong; final sigmoid head
  cvt4<<<dim3(1024), 256, 0, stream>>>(out, h0, 262144);
  for (int i = 0; i < 20; ++i) {
    u16* hin = (i & 1) ? h1 : h0;
    u16* hout = (i & 1) ? h0 : h1;
    gemm_bt<2><<<dim3(64), 256, 0, stream>>>(hin, wlb + (long)i * 65536, hout,
                                             bl + (long)i * 256);
  }
  gemm_bt<3><<<dim3(64), 256, 0, stream>>>(h0, fwtb, d_out, fb);
}